// Round 9
// baseline (908.179 us; speedup 1.0000x reference)
//
#include <hip/hip_runtime.h>

// argmin_c ||x-c|| == argmin_c (||c||^2 - 2 x.c). Cross-term via 3 f16 MFMA
// GEMMs (exact hi/lo split of fp32, lo*lo dropped ~2^-22 rel).
// Round 9: fix round-8's missing wm*4 wave-row offset in the A-fragment LDS
// read (both wave-rows read tiles 0-3 -> half the rows wrong). Structure:
// 32x32x16 MFMA, 256x128 block, 4x2 wave tile, A via LDS (fragment-order,
// no transpose), B direct from global, B-frag loads hoisted ahead of MFMAs.
typedef __fp16 f16x2 __attribute__((ext_vector_type(2)));
typedef __fp16 f16x8 __attribute__((ext_vector_type(8)));
typedef float f32x16 __attribute__((ext_vector_type(16)));
typedef float f32x4 __attribute__((ext_vector_type(4)));

constexpr int MM = 32768;   // B*T tokens
constexpr int NN = 2048;    // clusters
constexpr int KK = 768;     // dim
constexpr int NKT16 = KK / 16;              // 48 k-units
constexpr int NA_U = (MM / 32) * NKT16;     // 49152 A units
constexpr int NB_U = (NN / 32) * NKT16;     //  3072 B units

// Workspace layout (bytes). Unit = 2048 B: hi 1KB + lo 1KB, 32 rows x 16 k.
// Within a 1KB part: lane L's 16 B at L*16 = elems (m=L&31, k=(L>>5)*8+j).
constexpr size_t WS_APACK = 0;
constexpr size_t WS_BPACK = WS_APACK + (size_t)MM * KK * 4;  // 100663296
constexpr size_t WS_CSQ   = WS_BPACK + (size_t)NN * KK * 4;  // 106954752
constexpr size_t WS_SLOT  = WS_CSQ + (size_t)NN * 4;         // 106962944
constexpr size_t WS_NEED  = WS_SLOT + (size_t)MM * 16 * 8;   // 111157248

__device__ __forceinline__ unsigned bc(f16x2 h) {
    return __builtin_bit_cast(unsigned, h);
}

// ---------------- fast path ----------------

__global__ __launch_bounds__(256)
void fragpack_kernel(const float* __restrict__ A, const float* __restrict__ Bc,
                     uint4* __restrict__ Ap, uint4* __restrict__ Bp) {
    const int task = blockIdx.x * 4 + (threadIdx.x >> 6);
    const int lane = threadIdx.x & 63;
    const bool isB = task >= NA_U;
    const int t = isB ? task - NA_U : task;
    const int tile = t / NKT16, kt = t % NKT16;
    const float* src = (isB ? Bc : A)
        + (size_t)(tile * 32 + (lane & 31)) * KK + kt * 16 + (lane >> 5) * 8;
    uint4* dst = (isB ? Bp : Ap) + (size_t)t * 128 + lane;   // hi: +0, lo: +64

    const float4 v0 = *(const float4*)(src);
    const float4 v1 = *(const float4*)(src + 4);
    f16x2 h0 = __builtin_amdgcn_cvt_pkrtz(v0.x, v0.y);
    f16x2 h1 = __builtin_amdgcn_cvt_pkrtz(v0.z, v0.w);
    f16x2 h2 = __builtin_amdgcn_cvt_pkrtz(v1.x, v1.y);
    f16x2 h3 = __builtin_amdgcn_cvt_pkrtz(v1.z, v1.w);
    f16x2 l0 = __builtin_amdgcn_cvt_pkrtz(v0.x-(float)h0[0], v0.y-(float)h0[1]);
    f16x2 l1 = __builtin_amdgcn_cvt_pkrtz(v0.z-(float)h1[0], v0.w-(float)h1[1]);
    f16x2 l2 = __builtin_amdgcn_cvt_pkrtz(v1.x-(float)h2[0], v1.y-(float)h2[1]);
    f16x2 l3 = __builtin_amdgcn_cvt_pkrtz(v1.z-(float)h3[0], v1.w-(float)h3[1]);
    uint4 hv = {bc(h0), bc(h1), bc(h2), bc(h3)};
    uint4 lv = {bc(l0), bc(l1), bc(l2), bc(l3)};
    dst[0]  = hv;
    dst[64] = lv;
}

__global__ __launch_bounds__(64)
void csq_kernel(const float* __restrict__ cc, float* __restrict__ csq) {
    const int cl = blockIdx.x;
    const int lane = threadIdx.x;
    const float4* row = reinterpret_cast<const float4*>(cc + (size_t)cl * KK);
    float s = 0.f;
#pragma unroll
    for (int w = 0; w < KK / (4 * 64); ++w) {
        float4 v = row[w * 64 + lane];
        s = fmaf(v.x, v.x, s); s = fmaf(v.y, v.y, s);
        s = fmaf(v.z, v.z, s); s = fmaf(v.w, v.w, s);
    }
#pragma unroll
    for (int off = 32; off > 0; off >>= 1) s += __shfl_xor(s, off, 64);
    if (lane == 0) csq[cl] = s;
}

#define MF32(a, b, c) __builtin_amdgcn_mfma_f32_32x32x16_f16( \
    __builtin_bit_cast(f16x8, a), __builtin_bit_cast(f16x8, b), c, 0, 0, 0)

// Block: 256 rows (8 tiles32) x 128 cols (4 tiles32). 4 waves 2x2, wave tile
// 128x64 = 4(i) x 2(j) MFMA tiles, acc 8x16 f32. K-tile = 32 (2 k-units).
__global__ __launch_bounds__(256, 2)
void gemm32_kernel(const uint4* __restrict__ Ap, const uint4* __restrict__ Bp,
                   const float* __restrict__ csq, uint2* __restrict__ slots) {
    __shared__ uint4 lds[2048];   // 32 KB: chunk c = si*4 + part*2 + ks, 64 uint4

    const int gx = blockIdx.x;    // n-block 0..15
    const int gy = blockIdx.y;    // m-block 0..127
    const int tid  = threadIdx.x;
    const int lane = tid & 63;
    const int l31  = lane & 31;
    const int half = lane >> 5;
    const int wave = tid >> 6;
    const int wm = wave >> 1, wn = wave & 1;

    // A staging: 32 chunks of 1KB; thread t -> chunk c=t>>3, l8=t&7 (128 B).
    const int c  = tid >> 3, l8 = tid & 7;
    const int si = c >> 2, spart = (c >> 1) & 1, sks = c & 1;
    const uint4* aBase = Ap + ((size_t)(gy * 8 + si) * NKT16 + sks) * 128
                            + spart * 64 + l8;
    const int ldsW = c * 64 + l8;

    // B direct-global fragment pointers: col-tile ct = gx*4 + wn*2 + j.
    const uint4* bBase[2];
#pragma unroll
    for (int j = 0; j < 2; ++j)
        bBase[j] = Bp + (size_t)(gx * 4 + wn * 2 + j) * NKT16 * 128 + lane;

    f32x16 acc[4][2];
#pragma unroll
    for (int i = 0; i < 4; ++i)
#pragma unroll
        for (int j = 0; j < 2; ++j)
#pragma unroll
            for (int r = 0; r < 16; ++r) acc[i][j][r] = 0.f;

    uint4 st[8];
#pragma unroll
    for (int q = 0; q < 8; ++q) st[q] = aBase[q * 8];

#pragma unroll 1
    for (int kt2 = 0; kt2 < NKT16 / 2; ++kt2) {
        __syncthreads();                       // prev compute done with LDS
#pragma unroll
        for (int q = 0; q < 8; ++q) lds[ldsW + q * 8] = st[q];
        __syncthreads();
        if (kt2 + 1 < NKT16 / 2) {
            const size_t o = (size_t)(kt2 + 1) * 256;
#pragma unroll
            for (int q = 0; q < 8; ++q) st[q] = aBase[o + q * 8];
        }
        // Hoist all B fragment loads for both ks: issue before any MFMA.
        uint4 bfr[2][2][2];                    // [ks][j][part]
#pragma unroll
        for (int ks = 0; ks < 2; ++ks)
#pragma unroll
            for (int j = 0; j < 2; ++j) {
                const int kt = kt2 * 2 + ks;
                bfr[ks][j][0] = bBase[j][kt * 128];
                bfr[ks][j][1] = bBase[j][kt * 128 + 64];
            }
#pragma unroll
        for (int ks = 0; ks < 2; ++ks) {
            uint4 afr[4][2];
#pragma unroll
            for (int i = 0; i < 4; ++i) {
                afr[i][0] = lds[((wm * 4 + i) * 4 + 0 * 2 + ks) * 64 + lane];
                afr[i][1] = lds[((wm * 4 + i) * 4 + 1 * 2 + ks) * 64 + lane];
            }
#pragma unroll
            for (int i = 0; i < 4; ++i)
#pragma unroll
                for (int j = 0; j < 2; ++j)
                    acc[i][j] = MF32(afr[i][0], bfr[ks][j][0], acc[i][j]);
#pragma unroll
            for (int i = 0; i < 4; ++i)
#pragma unroll
                for (int j = 0; j < 2; ++j)
                    acc[i][j] = MF32(afr[i][0], bfr[ks][j][1], acc[i][j]);
#pragma unroll
            for (int i = 0; i < 4; ++i)
#pragma unroll
                for (int j = 0; j < 2; ++j)
                    acc[i][j] = MF32(afr[i][1], bfr[ks][j][0], acc[i][j]);
        }
    }

    // Epilogue. 32x32 C/D: col = lane&31, row = (r&3) + 8*(r>>2) + 4*half.
    const int cb = gx * 128;
    float csqv[2];
#pragma unroll
    for (int j = 0; j < 2; ++j) csqv[j] = csq[cb + wn * 64 + j * 32 + l31];

    __syncthreads();                   // LDS tiles dead; reuse for row tables
    float* vtab = (float*)&lds[0];     // [256 rows][2 wn]
    int*   itab = (int*)&lds[128];
#pragma unroll
    for (int i = 0; i < 4; ++i) {
#pragma unroll
        for (int r = 0; r < 16; ++r) {
            float v0 = csqv[0] - 2.0f * acc[i][0][r];
            int   i0 = cb + wn * 64 + l31;
            const float v1 = csqv[1] - 2.0f * acc[i][1][r];
            const int   i1 = cb + wn * 64 + 32 + l31;
            if (v1 < v0) { v0 = v1; i0 = i1; }           // j ascending, strict <
#pragma unroll
            for (int off = 1; off < 32; off <<= 1) {     // 32 col-lanes per half
                const float ov = __shfl_xor(v0, off, 64);
                const int   oi = __shfl_xor(i0, off, 64);
                if (ov < v0 || (ov == v0 && oi < i0)) { v0 = ov; i0 = oi; }
            }
            if (l31 == 0) {
                const int row = wm * 128 + i * 32 + (r & 3) + 8 * (r >> 2) + 4 * half;
                vtab[row * 2 + wn] = v0;
                itab[row * 2 + wn] = i0;
            }
        }
    }
    __syncthreads();
    {
        float v0 = vtab[tid * 2]; int i0 = itab[tid * 2];
        const float v1 = vtab[tid * 2 + 1]; const int i1 = itab[tid * 2 + 1];
        if (v1 < v0 || (v1 == v0 && i1 < i0)) { v0 = v1; i0 = i1; }
        uint2 e; e.x = __float_as_uint(v0); e.y = (unsigned)i0;
        slots[(size_t)(gy * 256 + tid) * 16 + gx] = e;
    }
}

__global__ __launch_bounds__(256)
void slot_reduce_kernel(const uint2* __restrict__ slots, int* __restrict__ out) {
    const int t = blockIdx.x * 256 + threadIdx.x;
    const uint2* s = slots + (size_t)t * 16;
    float bv = __uint_as_float(s[0].x); int bi = (int)s[0].y;
#pragma unroll
    for (int j = 1; j < 16; ++j) {
        const uint2 e = s[j];
        const float v = __uint_as_float(e.x);
        if (v < bv || (v == bv && (int)e.y < bi)) { bv = v; bi = (int)e.y; }
    }
    out[t] = bi;
}

// ---------------- round-3 fallback (proven, used only if ws too small) ------

__global__ __launch_bounds__(256)
void init_ws_kernel(unsigned long long* __restrict__ w) {
    w[blockIdx.x * 256 + threadIdx.x] = 0xFFFFFFFFFFFFFFFFull;
}

__global__ __launch_bounds__(256, 2)
void argmin_mfma_kernel(const float* __restrict__ A, const float* __restrict__ Bc,
                        const float* __restrict__ csq,
                        unsigned long long* __restrict__ ws64) {
    __shared__ unsigned lds[4 * 128 * 20];
    constexpr int AH = 0, AL = 2560, BH = 5120;

    const int tid  = threadIdx.x;
    const int lane = tid & 63;
    const int ln15 = lane & 15;
    const int quad = lane >> 4;
    const int wave = tid >> 6;
    const int wm = wave >> 1, wn = wave & 1;
    const int tbase = blockIdx.x * 128;
    const int cb    = blockIdx.y * 128;

    const int sr  = tid >> 1;
    const int skh = tid & 1;
    const float* gA = A  + (size_t)(tbase + sr) * KK + skh * 16;
    const float* gB = Bc + (size_t)(cb   + sr) * KK + skh * 16;
    const int wword = sr * 20 + skh * 8;

    f32x4 acc[4][4];
#pragma unroll
    for (int i = 0; i < 4; ++i)
#pragma unroll
        for (int j = 0; j < 4; ++j) { f32x4 z = {0.f,0.f,0.f,0.f}; acc[i][j] = z; }

    float4 av[4], bv[4];
#pragma unroll
    for (int p = 0; p < 4; ++p) {
        av[p] = *(const float4*)(gA + p * 4);
        bv[p] = *(const float4*)(gB + p * 4);
    }

    int aw[4], bw[4];
#pragma unroll
    for (int i = 0; i < 4; ++i) {
        aw[i] = AH + (wm * 64 + i * 16 + ln15) * 20 + quad * 4;
        bw[i] = BH + (wn * 64 + i * 16 + ln15) * 20 + quad * 4;
    }

    for (int k0 = 0; k0 < KK; k0 += 32) {
        __syncthreads();
#pragma unroll
        for (int h = 0; h < 2; ++h) {
            float4 v0 = av[2*h], v1 = av[2*h+1];
            f16x2 h00 = __builtin_amdgcn_cvt_pkrtz(v0.x, v0.y);
            f16x2 h01 = __builtin_amdgcn_cvt_pkrtz(v0.z, v0.w);
            f16x2 h10 = __builtin_amdgcn_cvt_pkrtz(v1.x, v1.y);
            f16x2 h11 = __builtin_amdgcn_cvt_pkrtz(v1.z, v1.w);
            f16x2 l00 = __builtin_amdgcn_cvt_pkrtz(v0.x-(float)h00[0], v0.y-(float)h00[1]);
            f16x2 l01 = __builtin_amdgcn_cvt_pkrtz(v0.z-(float)h01[0], v0.w-(float)h01[1]);
            f16x2 l10 = __builtin_amdgcn_cvt_pkrtz(v1.x-(float)h10[0], v1.y-(float)h10[1]);
            f16x2 l11 = __builtin_amdgcn_cvt_pkrtz(v1.z-(float)h11[0], v1.w-(float)h11[1]);
            uint4 hv = {bc(h00), bc(h01), bc(h10), bc(h11)};
            uint4 lv = {bc(l00), bc(l01), bc(l10), bc(l11)};
            *(uint4*)&lds[AH + wword + 4*h] = hv;
            *(uint4*)&lds[AL + wword + 4*h] = lv;

            float4 w0 = bv[2*h], w1 = bv[2*h+1];
            f16x2 g00 = __builtin_amdgcn_cvt_pkrtz(w0.x, w0.y);
            f16x2 g01 = __builtin_amdgcn_cvt_pkrtz(w0.z, w0.w);
            f16x2 g10 = __builtin_amdgcn_cvt_pkrtz(w1.x, w1.y);
            f16x2 g11 = __builtin_amdgcn_cvt_pkrtz(w1.z, w1.w);
            f16x2 m00 = __builtin_amdgcn_cvt_pkrtz(w0.x-(float)g00[0], w0.y-(float)g00[1]);
            f16x2 m01 = __builtin_amdgcn_cvt_pkrtz(w0.z-(float)g01[0], w0.w-(float)g01[1]);
            f16x2 m10 = __builtin_amdgcn_cvt_pkrtz(w1.x-(float)g10[0], w1.y-(float)g10[1]);
            f16x2 m11 = __builtin_amdgcn_cvt_pkrtz(w1.z-(float)g11[0], w1.w-(float)g11[1]);
            uint4 gv = {bc(g00), bc(g01), bc(g10), bc(g11)};
            uint4 mv = {bc(m00), bc(m01), bc(m10), bc(m11)};
            *(uint4*)&lds[BH + wword + 4*h]        = gv;
            *(uint4*)&lds[BH + 2560 + wword + 4*h] = mv;
        }
        __syncthreads();

        const int kn = k0 + 32;
        if (kn < KK) {
#pragma unroll
            for (int p = 0; p < 4; ++p) {
                av[p] = *(const float4*)(gA + kn + p * 4);
                bv[p] = *(const float4*)(gB + kn + p * 4);
            }
        }

        f16x8 a_h[4], a_l[4], b_h[4], b_l[4];
#pragma unroll
        for (int i = 0; i < 4; ++i) {
            a_h[i] = *(const f16x8*)&lds[aw[i]];
            a_l[i] = *(const f16x8*)&lds[aw[i] + 2560];
            b_h[i] = *(const f16x8*)&lds[bw[i]];
            b_l[i] = *(const f16x8*)&lds[bw[i] + 2560];
        }
#pragma unroll
        for (int i = 0; i < 4; ++i)
#pragma unroll
            for (int j = 0; j < 4; ++j) {
                acc[i][j] = __builtin_amdgcn_mfma_f32_16x16x32_f16(a_h[i], b_h[j], acc[i][j], 0, 0, 0);
                acc[i][j] = __builtin_amdgcn_mfma_f32_16x16x32_f16(a_h[i], b_l[j], acc[i][j], 0, 0, 0);
                acc[i][j] = __builtin_amdgcn_mfma_f32_16x16x32_f16(a_l[i], b_h[j], acc[i][j], 0, 0, 0);
            }
    }

    float csq4[4];
#pragma unroll
    for (int j = 0; j < 4; ++j) csq4[j] = csq[cb + wn * 64 + j * 16 + ln15];

    float bval[16]; int bidx[16];
#pragma unroll
    for (int i = 0; i < 4; ++i)
#pragma unroll
        for (int r = 0; r < 4; ++r) {
            const int rid = i * 4 + r;
            float bv_ = csq4[0] - 2.0f * acc[i][0][r];
            int   bi_ = cb + wn * 64 + ln15;
#pragma unroll
            for (int j = 1; j < 4; ++j) {
                const float s = csq4[j] - 2.0f * acc[i][j][r];
                const int   c2 = cb + wn * 64 + j * 16 + ln15;
                if (s < bv_) { bv_ = s; bi_ = c2; }
            }
            bval[rid] = bv_; bidx[rid] = bi_;
        }
#pragma unroll
    for (int off = 1; off < 16; off <<= 1) {
#pragma unroll
        for (int rid = 0; rid < 16; ++rid) {
            const float ov = __shfl_xor(bval[rid], off, 64);
            const int   oi = __shfl_xor(bidx[rid], off, 64);
            if (ov < bval[rid] || (ov == bval[rid] && oi < bidx[rid])) {
                bval[rid] = ov; bidx[rid] = oi;
            }
        }
    }

    __syncthreads();
    float* vtab = (float*)&lds[0];
    int*   itab = (int*)&lds[256];
    if (ln15 == 0) {
#pragma unroll
        for (int i = 0; i < 4; ++i)
#pragma unroll
            for (int r = 0; r < 4; ++r) {
                const int row = wm * 64 + i * 16 + quad * 4 + r;
                vtab[row * 2 + wn] = bval[i * 4 + r];
                itab[row * 2 + wn] = bidx[i * 4 + r];
            }
    }
    __syncthreads();
    if (tid < 128) {
        float v0 = vtab[tid * 2]; int i0 = itab[tid * 2];
        const float v1 = vtab[tid * 2 + 1]; const int i1 = itab[tid * 2 + 1];
        if (v1 < v0 || (v1 == v0 && i1 < i0)) { v0 = v1; i0 = i1; }
        const unsigned b   = __float_as_uint(v0);
        const unsigned key = (b & 0x80000000u) ? ~b : (b | 0x80000000u);
        const unsigned long long pk =
            ((unsigned long long)key << 32) | (unsigned long long)(unsigned)i0;
        atomicMin(&ws64[tbase + tid], pk);
    }
}

__global__ __launch_bounds__(256)
void unpack_kernel(const unsigned long long* __restrict__ w, int* __restrict__ out) {
    const int i = blockIdx.x * 256 + threadIdx.x;
    out[i] = (int)(unsigned)(w[i] & 0xFFFFFFFFull);
}

extern "C" void kernel_launch(void* const* d_in, const int* in_sizes, int n_in,
                              void* d_out, int out_size, void* d_ws, size_t ws_size,
                              hipStream_t stream) {
    const float* embed   = (const float*)d_in[0];   // [32768][768] fp32
    const float* centers = (const float*)d_in[1];   // [2048][768] fp32
    int* out = (int*)d_out;                         // [32768] int32

    if (ws_size >= WS_NEED) {
        uint4* Ap = (uint4*)((char*)d_ws + WS_APACK);
        uint4* Bp = (uint4*)((char*)d_ws + WS_BPACK);
        float* csq   = (float*)((char*)d_ws + WS_CSQ);
        uint2* slots = (uint2*)((char*)d_ws + WS_SLOT);
        fragpack_kernel<<<(NA_U + NB_U) / 4, 256, 0, stream>>>(
            embed, centers, Ap, Bp);
        csq_kernel<<<NN, 64, 0, stream>>>(centers, csq);
        gemm32_kernel<<<dim3(NN / 128, MM / 256), 256, 0, stream>>>(
            Ap, Bp, csq, slots);
        slot_reduce_kernel<<<MM / 256, 256, 0, stream>>>(slots, out);
    } else {
        unsigned long long* ws64 = (unsigned long long*)d_ws;
        float* csq = (float*)((char*)d_ws + (size_t)MM * 8);
        init_ws_kernel<<<MM / 256, 256, 0, stream>>>(ws64);
        csq_kernel<<<NN, 64, 0, stream>>>(centers, csq);
        argmin_mfma_kernel<<<dim3(MM / 128, NN / 128), 256, 0, stream>>>(
            embed, centers, csq, ws64);
        unpack_kernel<<<MM / 256, 256, 0, stream>>>(ws64, out);
    }
}